// Round 13
// baseline (106.468 us; speedup 1.0000x reference)
//
#include <hip/hip_runtime.h>
#include <hip/hip_bf16.h>
#include <float.h>

// Problem constants (fixed by setup_inputs)
constexpr int B = 8, N = 4096, M = 4096, E = 12288;
constexpr int TB = 512;
constexpr int EDGE_BLOCKS = (B * E) / TB;       // 192 (first in grid)
constexpr int SWEEP_BLOCKS = 2 * B * 16;        // 256: dir x b x ngroup
// ws layout:
//   shorts [0 .. 1048576)  bfrag: 2 clouds x 32768 pts x 16 shorts (2 MB)
// float offsets:
constexpr size_t MINV = 524288;                  // [d][b][4096] row mins = 65536
constexpr size_t EOFF = 589824;                  // 2*192 edge partials
// All slots written unconditionally -> 0xAA poison harmless, no init kernel.

typedef short bf16x8  __attribute__((ext_vector_type(8)));
typedef float f32x16  __attribute__((ext_vector_type(16)));

__device__ __forceinline__ unsigned short f2bf(float x) {
    unsigned u = __float_as_uint(x);
    unsigned r = u + 0x7FFFu + ((u >> 16) & 1u);   // RNE
    return (unsigned short)(r >> 16);
}
__device__ __forceinline__ float bf2f(unsigned short h) {
    return __uint_as_float(((unsigned)h) << 16);
}
constexpr unsigned short BF_ONE = 0x3F80;

// ---- pack BOTH clouds into MFMA B-fragments (lane-ordered, 16B stores) ----
// Layout per point j of cloud cc (PROVEN in R12, absmax 0):
//   k0..7  (lanes 0-31):  -2x_h,-2x_h,-2x_l,-2x_l, -2y_h,-2y_h,-2y_l,-2y_l
//   k8..15 (lanes 32-63): -2z_h,-2z_h,-2z_l,-2z_l, |p|^2_h,|p|^2_l, 1, 1
__global__ __launch_bounds__(256) void pack_kernel(
    const float* __restrict__ pred, const float* __restrict__ gt,
    unsigned short* __restrict__ bfrag) {
    const int i  = blockIdx.x * 256 + threadIdx.x;  // 0..65535
    const int cc = i >> 15;                          // 0=pred, 1=gt
    const int j  = i & 32767;
    const float* p = (cc ? gt : pred) + (size_t)j * 3;
    const float x = p[0], y = p[1], z = p[2];
    const unsigned short hx = f2bf(x), hy = f2bf(y), hz = f2bf(z);
    const unsigned short lx = f2bf(x - bf2f(hx));
    const unsigned short ly = f2bf(y - bf2f(hy));
    const unsigned short lz = f2bf(z - bf2f(hz));
    const float c = x * x + y * y + z * z;
    const unsigned short ch = f2bf(c);
    const unsigned short cl = f2bf(c - bf2f(ch));
    const unsigned short ax = f2bf(-2.f * bf2f(hx)), bx = f2bf(-2.f * bf2f(lx));
    const unsigned short ay = f2bf(-2.f * bf2f(hy)), by = f2bf(-2.f * bf2f(ly));
    const unsigned short az = f2bf(-2.f * bf2f(hz)), bz = f2bf(-2.f * bf2f(lz));

    bf16x8 v0, v1;
    v0[0] = (short)ax; v0[1] = (short)ax; v0[2] = (short)bx; v0[3] = (short)bx;
    v0[4] = (short)ay; v0[5] = (short)ay; v0[6] = (short)by; v0[7] = (short)by;
    v1[0] = (short)az; v1[1] = (short)az; v1[2] = (short)bz; v1[3] = (short)bz;
    v1[4] = (short)ch; v1[5] = (short)cl; v1[6] = (short)BF_ONE; v1[7] = (short)BF_ONE;

    unsigned short* base =
        bfrag + (size_t)cc * 524288 + ((size_t)(j >> 5) * 64 + (j & 31)) * 8;
    *(bf16x8*)base         = v0;     // lanes 0-31 fragment
    *(bf16x8*)(base + 256) = v1;     // lanes 32-63 fragment
}

// ---- fused: edge blocks (bid<192) + row-min MFMA sweep blocks ----
__global__ __launch_bounds__(TB) void sweep_kernel(
    const float* __restrict__ pred, const float* __restrict__ gt,
    const unsigned short* __restrict__ bfrag, const int* __restrict__ edges,
    float* __restrict__ wsf) {
    const int bid = blockIdx.x;
    const int t = threadIdx.x;
    __shared__ float wsum[8], wsum2[8];

    if (bid >= EDGE_BLOCKS) {
        // -------- chamfer sweep: one direction, pure row-mins --------
        const int sb = bid - EDGE_BLOCKS;          // 0..255
        const int d  = sb >> 7;                    // 0: q=pred/ref=gt, 1: swapped
        const int b  = (sb >> 4) & 7;
        const int ng = sb & 15;
        const int wv = t >> 6, l = t & 63;
        const int nt = ng * 8 + wv;                // this wave's 32-row tile

        // A-fragment from this direction's query cloud (layout PROVEN in R12)
        const float* qsrc = d ? gt : pred;
        const float* qp = qsrc + (size_t)(b * 4096 + nt * 32 + (l & 31)) * 3;
        const float x = qp[0], y = qp[1], z = qp[2];
        const unsigned short hx = f2bf(x), hy = f2bf(y), hz = f2bf(z);
        const unsigned short lx = f2bf(x - bf2f(hx));
        const unsigned short ly = f2bf(y - bf2f(hy));
        const unsigned short lz = f2bf(z - bf2f(hz));
        const float dd = x * x + y * y + z * z;
        const unsigned short dh = f2bf(dd);
        const unsigned short dl = f2bf(dd - bf2f(dh));
        bf16x8 af;
        if (l < 32) {
            af[0] = (short)hx; af[1] = (short)lx; af[2] = (short)hx; af[3] = (short)lx;
            af[4] = (short)hy; af[5] = (short)ly; af[6] = (short)hy; af[7] = (short)ly;
        } else {
            af[0] = (short)hz; af[1] = (short)lz; af[2] = (short)hz; af[3] = (short)lz;
            af[4] = (short)BF_ONE; af[5] = (short)BF_ONE; af[6] = (short)dh; af[7] = (short)dl;
        }

        // B: all 128 ref tiles of the OTHER cloud, depth-2 register prefetch
        const unsigned short* bp =
            bfrag + (size_t)(1 - d) * 524288 + ((size_t)(b * 128) * 64 + l) * 8;
        float rowacc[16];
#pragma unroll
        for (int r = 0; r < 16; ++r) rowacc[r] = FLT_MAX;
        f32x16 zacc = {};

        bf16x8 b0 = *(const bf16x8*)bp;
        bf16x8 b1 = *(const bf16x8*)(bp + 512);
#pragma unroll 2
        for (int mt = 0; mt < 128; ++mt) {
            bf16x8 bn = b1;
            if (mt + 2 < 128) bn = *(const bf16x8*)(bp + (size_t)(mt + 2) * 512);
            const f32x16 D = __builtin_amdgcn_mfma_f32_32x32x16_bf16(af, b0, zacc, 0, 0, 0);
#pragma unroll
            for (int r = 0; r < 16; ++r) rowacc[r] = fminf(rowacc[r], D[r]);
            b0 = b1; b1 = bn;
        }

        // once-per-block: min across the 32 columns held in lanes
#pragma unroll
        for (int r = 0; r < 16; ++r) {
            float v = rowacc[r];
            v = fminf(v, __shfl_xor(v, 1, 64));
            v = fminf(v, __shfl_xor(v, 2, 64));
            v = fminf(v, __shfl_xor(v, 4, 64));
            v = fminf(v, __shfl_xor(v, 8, 64));
            v = fminf(v, __shfl_xor(v, 16, 64));
            rowacc[r] = v;
        }
        if ((l & 31) == 0) {                       // lanes 0 and 32
            float* rp = wsf + MINV + (size_t)(d * 8 + b) * 4096 + (size_t)nt * 32;
            const int hb = (l >> 5) * 4;
#pragma unroll
            for (int r = 0; r < 16; ++r)
                rp[(r & 3) + 8 * (r >> 2) + hb] = fmaxf(rowacc[r], 0.f);
        }
    } else {
        // ---------------- edge-length block ----------------
        const int eg = bid * TB + t;               // 0..98303
        const int b  = eg / E;
        const int e  = eg - b * E;
        const int i0 = edges[2 * e], i1 = edges[2 * e + 1];
        const float* p0 = pred + ((size_t)b * N + i0) * 3;
        const float* p1 = pred + ((size_t)b * N + i1) * 3;
        const float dx = p0[0] - p1[0];
        const float dy = p0[1] - p1[1];
        const float dz = p0[2] - p1[2];
        float L  = sqrtf(dx * dx + dy * dy + dz * dz);
        float L2 = L * L;
#pragma unroll
        for (int o = 32; o > 0; o >>= 1) {
            L  += __shfl_down(L, o, 64);
            L2 += __shfl_down(L2, o, 64);
        }
        const int wv = t >> 6;
        if ((t & 63) == 0) { wsum[wv] = L; wsum2[wv] = L2; }
        __syncthreads();
        if (t == 0) {
            float a = 0.0f, c = 0.0f;
#pragma unroll
            for (int w = 0; w < 8; w++) { a += wsum[w]; c += wsum2[w]; }
            wsf[EOFF + 2 * bid]     = a;
            wsf[EOFF + 2 * bid + 1] = c;
        }
    }
}

// ---- single-block finish: sqrt-sum of 65536 mins + edge variance ----
__global__ __launch_bounds__(1024) void final_kernel(
    const float* __restrict__ wsf, float* __restrict__ out) {
    const int t = threadIdx.x;
    float sc = 0.0f;
#pragma unroll 8
    for (int k = 0; k < 64; ++k)
        sc += sqrtf(wsf[MINV + t + (size_t)k * 1024]);
    float s1 = 0.0f, s2 = 0.0f;
    if (t < EDGE_BLOCKS) {
        s1 = wsf[EOFF + 2 * t];
        s2 = wsf[EOFF + 2 * t + 1];
    }
#pragma unroll
    for (int o = 32; o > 0; o >>= 1) {
        sc += __shfl_down(sc, o, 64);
        s1 += __shfl_down(s1, o, 64);
        s2 += __shfl_down(s2, o, 64);
    }
    __shared__ float w[3][16];
    const int wv = t >> 6, ln = t & 63;
    if (ln == 0) { w[0][wv] = sc; w[1][wv] = s1; w[2][wv] = s2; }
    __syncthreads();
    if (t == 0) {
        float S = 0.f, A = 0.f, C = 0.f;
#pragma unroll
        for (int i = 0; i < 16; i++) { S += w[0][i]; A += w[1][i]; C += w[2][i]; }
        const float K = (float)(B * E);            // 98304
        const float var = (C - A * A / K) / (K - 1.0f);
        out[0] = S / 32768.0f + 0.1f * var;        // cd + 0.1 * edge_var
    }
}

extern "C" void kernel_launch(void* const* d_in, const int* in_sizes, int n_in,
                              void* d_out, int out_size, void* d_ws, size_t ws_size,
                              hipStream_t stream) {
    const float* pred  = (const float*)d_in[0];
    const float* gt    = (const float*)d_in[1];
    const int*   edges = (const int*)d_in[2];
    float* out = (float*)d_out;
    float* wsf = (float*)d_ws;
    unsigned short* bfrag = (unsigned short*)d_ws;

    pack_kernel<<<256, 256, 0, stream>>>(pred, gt, bfrag);
    sweep_kernel<<<EDGE_BLOCKS + SWEEP_BLOCKS, TB, 0, stream>>>(pred, gt, bfrag, edges, wsf);
    final_kernel<<<1, 1024, 0, stream>>>(wsf, out);
}